// Round 7
// baseline (401.927 us; speedup 1.0000x reference)
//
#include <hip/hip_runtime.h>
#include <hip/hip_fp16.h>

#define CCH 64      // channels
#define RPB 32      // rows per bucket (dst_local fits 5 bits)
#define PCH 8192    // edges per partition block
#define NBMAX 1568  // >= NB = ceil(50000/32) = 1563

// ---------------- zero int buffer ----------------
__global__ void k_zero(int* __restrict__ p, int n) {
    int i = blockIdx.x * blockDim.x + threadIdx.x;
    if (i < n) p[i] = 0;
}

// ---- pass A: per-block bucket histogram -> H[c][blk][b]; also cnt totals ----
__global__ void __launch_bounds__(256) k_hist(const int* __restrict__ e0,
        const int* __restrict__ e1, const int* __restrict__ e2,
        int* __restrict__ H, int* __restrict__ cnt, int E, int NB, int NBLK) {
    int c = blockIdx.y;
    const int* dd = ((c == 0) ? e0 : (c == 1) ? e1 : e2) + E;
    int base = blockIdx.x * PCH;
    int nE = E - base; if (nE > PCH) nE = PCH;
    __shared__ int hist[NBMAX];
    int t = threadIdx.x;
    for (int i = t; i < NB; i += 256) hist[i] = 0;
    __syncthreads();
    for (int k = t; k < nE; k += 256) atomicAdd(&hist[dd[base + k] >> 5], 1);
    __syncthreads();
    int* Hrow = H + ((size_t)c * NBLK + blockIdx.x) * NB;
    for (int i = t; i < NB; i += 256) {
        int h = hist[i];
        Hrow[i] = h;
        if (h) atomicAdd(&cnt[c * NB + i], h);
    }
}

// ---- exclusive scan of NB bucket totals per conv -> bstart ----
__global__ void __launch_bounds__(1024) k_bscan(const int* __restrict__ cnt,
        int* __restrict__ bstart, int NB, int E) {
    int c = blockIdx.x, t = threadIdx.x;
    __shared__ int sm[1024];
    int i0 = 2 * t, i1 = 2 * t + 1;
    int v0 = (i0 < NB) ? cnt[c * NB + i0] : 0;
    int v1 = (i1 < NB) ? cnt[c * NB + i1] : 0;
    sm[t] = v0 + v1;
    __syncthreads();
    #pragma unroll
    for (int off = 1; off < 1024; off <<= 1) {
        int u = (t >= off) ? sm[t - off] : 0;
        __syncthreads();
        sm[t] += u;
        __syncthreads();
    }
    int ex = sm[t] - (v0 + v1);
    if (i0 < NB) bstart[c * (NB + 1) + i0] = ex;
    if (i1 < NB) bstart[c * (NB + 1) + i1] = ex + v0;
    if (t == 0) bstart[c * (NB + 1) + NB] = E;
}

// ---- pass B: per-bucket scan over blocks: H <- bstart[b] + prefix(H) ----
__global__ void __launch_bounds__(256) k_colscan(int* __restrict__ H,
        const int* __restrict__ bstart, int NB, int NBLK) {
    int c = blockIdx.y;
    int b = blockIdx.x * 4 + (threadIdx.x >> 6);
    if (b >= NB) return;
    int l = threadIdx.x & 63;
    int* Hc = H + (size_t)c * NBLK * NB;
    int v0 = (l < NBLK) ? Hc[(size_t)l * NB + b] : 0;
    int v1 = (64 + l < NBLK) ? Hc[(size_t)(64 + l) * NB + b] : 0;
    int s0 = v0;
    #pragma unroll
    for (int off = 1; off < 64; off <<= 1) {
        int u = __shfl_up(s0, off, 64);
        if (l >= off) s0 += u;
    }
    int tot0 = __shfl(s0, 63, 64);
    int s1 = v1;
    #pragma unroll
    for (int off = 1; off < 64; off <<= 1) {
        int u = __shfl_up(s1, off, 64);
        if (l >= off) s1 += u;
    }
    int base = bstart[c * (NB + 1) + b];
    if (l < NBLK) Hc[(size_t)l * NB + b] = base + s0 - v0;
    if (64 + l < NBLK) Hc[(size_t)(64 + l) * NB + b] = base + tot0 + s1 - v1;
}

// ---- pass C: place edges into exclusive slot ranges (LDS cursors only) ----
__global__ void __launch_bounds__(256) k_part2(const int* __restrict__ e0,
        const int* __restrict__ e1, const int* __restrict__ e2,
        const int* __restrict__ H, unsigned* __restrict__ bdata,
        int E, int NB, int NBLK) {
    int c = blockIdx.y;
    const int* ed = (c == 0) ? e0 : (c == 1) ? e1 : e2;
    int base = blockIdx.x * PCH;
    int nE = E - base; if (nE > PCH) nE = PCH;
    __shared__ int cur[NBMAX];
    const int* Hrow = H + ((size_t)c * NBLK + blockIdx.x) * NB;
    int t = threadIdx.x;
    for (int i = t; i < NB; i += 256) cur[i] = Hrow[i];
    __syncthreads();
    unsigned* bo = bdata + (size_t)c * E;
    for (int k = t; k < nE; k += 256) {
        int s = ed[base + k];
        int d = ed[E + base + k];
        int slot = atomicAdd(&cur[d >> 5], 1);
        bo[slot] = (unsigned)s | ((unsigned)(d & 31) << 16);
    }
}

// ---- within-bucket 32-way counting sort -> row-sorted src list + CSR + dinv ----
__global__ void __launch_bounds__(256) k_sort32(const unsigned* __restrict__ bdata,
        const int* __restrict__ bstart, int* __restrict__ sdat,
        int* __restrict__ rs, float* __restrict__ dinv, int E, int N, int NB) {
    int b = blockIdx.x, c = blockIdx.y;
    __shared__ int cnt[RPB];
    __shared__ int cur[RPB];
    int t = threadIdx.x;
    if (t < RPB) cnt[t] = 0;
    __syncthreads();
    int beg = bstart[c * (NB + 1) + b];
    int end = bstart[c * (NB + 1) + b + 1];
    const unsigned* bd = bdata + (size_t)c * E;
    for (int i = beg + t; i < end; i += 256) atomicAdd(&cnt[bd[i] >> 16], 1);
    __syncthreads();
    if (t < 64) {                       // wave 0: scan the 32 counters
        int v = (t < RPB) ? cnt[t] : 0;
        int s = v;
        #pragma unroll
        for (int off = 1; off < RPB; off <<= 1) {
            int u = __shfl_up(s, off, 64);
            if (t >= off) s += u;
        }
        if (t < RPB) {
            int ex = beg + s - v;       // exclusive row start
            cur[t] = ex;
            int row = b * RPB + t;
            if (row < N) {
                rs[c * (N + 1) + row] = ex;
                dinv[c * N + row] = rsqrtf((float)(v + 1));
            }
        }
        if (b == NB - 1 && t == 0) rs[c * (N + 1) + N] = E;
    }
    __syncthreads();
    int* so = sdat + (size_t)c * E;
    for (int i = beg + t; i < end; i += 256) {
        unsigned r = bd[i];
        int slot = atomicAdd(&cur[r >> 16], 1);
        so[slot] = (int)(r & 0xFFFFu);
    }
}

// ---- h16[c,row,:] = fp16( (x_row . W_c) * dinv[c,row] ) ----
__global__ void __launch_bounds__(256) k_gemm_all(const float* __restrict__ xs_,
        const float* __restrict__ xg_, const float* __restrict__ W0,
        const float* __restrict__ W1, const float* __restrict__ W2,
        const float* __restrict__ dinv, __half* __restrict__ h16, int N) {
    int c = blockIdx.y;
    const float* x = (c == 2) ? xg_ : xs_;
    const float* W = (c == 0) ? W0 : (c == 1) ? W1 : W2;
    __shared__ float Ws[CCH * CCH];
    __shared__ float xsm[16 * CCH];
    int t = threadIdx.x;
    #pragma unroll
    for (int j = 0; j < 4; ++j) {
        int idx = j * 1024 + t * 4;
        *(float4*)(Ws + idx) = *(const float4*)(W + idx);
    }
    int row0 = blockIdx.x * 16;
    {
        int idx = t * 4;
        int r = row0 + (idx >> 6);
        float4 v = make_float4(0.f, 0.f, 0.f, 0.f);
        if (r < N) v = *(const float4*)(x + (size_t)r * CCH + (idx & 63));
        *(float4*)(xsm + idx) = v;
    }
    __syncthreads();
    int lane = t & 63;
    int wv = t >> 6;
    float a0 = 0.f, a1 = 0.f, a2 = 0.f, a3 = 0.f;
    #pragma unroll
    for (int k = 0; k < CCH; ++k) {
        float w = Ws[k * CCH + lane];
        a0 += xsm[(wv * 4 + 0) * CCH + k] * w;
        a1 += xsm[(wv * 4 + 1) * CCH + k] * w;
        a2 += xsm[(wv * 4 + 2) * CCH + k] * w;
        a3 += xsm[(wv * 4 + 3) * CCH + k] * w;
    }
    const float* dv = dinv + c * N;
    __half* hc = h16 + (size_t)c * N * CCH;
    int r = row0 + wv * 4;
    if (r + 0 < N) hc[(size_t)(r + 0) * CCH + lane] = __float2half(a0 * dv[r + 0]);
    if (r + 1 < N) hc[(size_t)(r + 1) * CCH + lane] = __float2half(a1 * dv[r + 1]);
    if (r + 2 < N) hc[(size_t)(r + 2) * CCH + lane] = __float2half(a2 * dv[r + 2]);
    if (r + 3 < N) hc[(size_t)(r + 3) * CCH + lane] = __float2half(a3 * dv[r + 3]);
}

// ---- register-accumulating pull over one row's sorted src list ----
__device__ __forceinline__ float pull_conv(const int* __restrict__ sd,
        int beg, int end, const __half* __restrict__ hc, int lane) {
    float acc = 0.f;
    int i = beg;
    for (; i + 3 < end; i += 4) {       // 4 gathers in flight
        int s0 = sd[i], s1 = sd[i + 1], s2 = sd[i + 2], s3 = sd[i + 3];
        float v0 = __half2float(hc[(size_t)s0 * CCH + lane]);
        float v1 = __half2float(hc[(size_t)s1 * CCH + lane]);
        float v2 = __half2float(hc[(size_t)s2 * CCH + lane]);
        float v3 = __half2float(hc[(size_t)s3 * CCH + lane]);
        acc += (v0 + v1) + (v2 + v3);
    }
    for (; i < end; ++i)
        acc += __half2float(hc[(size_t)sd[i] * CCH + lane]);
    return acc;
}

// ---- fused pull: wave per row, lane = channel, register acc, no LDS ----
__global__ void __launch_bounds__(256) k_pull(const int* __restrict__ rs,
        const int* __restrict__ sdat, const __half* __restrict__ h16,
        const float* __restrict__ dinv,
        const float* __restrict__ b0, const float* __restrict__ b1,
        const float* __restrict__ b2,
        float* __restrict__ out, int N, int E) {
    int row = blockIdx.x * 4 + (threadIdx.x >> 6);
    if (row >= 2 * N) return;
    int lane = threadIdx.x & 63;
    size_t NC = (size_t)N * CCH;
    if (row < N) {                          // star: conv0 + conv1
        const int* rs0 = rs;
        const int* rs1 = rs + (N + 1);
        float a0 = pull_conv(sdat,     rs0[row], rs0[row + 1], h16,      lane);
        float a1 = pull_conv(sdat + E, rs1[row], rs1[row + 1], h16 + NC, lane);
        float dd0 = dinv[row], dd1 = dinv[N + row];
        float s0 = __half2float(h16[(size_t)row * CCH + lane]);
        float s1 = __half2float(h16[NC + (size_t)row * CCH + lane]);
        out[(size_t)row * CCH + lane] =
            (a0 + s0) * dd0 + (a1 + s1) * dd1 + b0[lane] + b1[lane];
    } else {                                // gal: conv2
        int r = row - N;
        const int* rs2 = rs + 2 * (N + 1);
        float a2 = pull_conv(sdat + 2 * (size_t)E, rs2[r], rs2[r + 1],
                             h16 + 2 * NC, lane);
        float dd2 = dinv[2 * N + r];
        float s2 = __half2float(h16[2 * NC + (size_t)r * CCH + lane]);
        out[NC + (size_t)r * CCH + lane] = (a2 + s2) * dd2 + b2[lane];
    }
}

static inline size_t align256(size_t x) { return (x + 255) & ~(size_t)255; }

extern "C" void kernel_launch(void* const* d_in, const int* in_sizes, int n_in,
                              void* d_out, int out_size, void* d_ws, size_t ws_size,
                              hipStream_t stream) {
    const float* x_star = (const float*)d_in[0];
    const float* x_gal  = (const float*)d_in[1];
    const int*   e_ssn  = (const int*)d_in[2];
    const int*   e_ssf  = (const int*)d_in[3];
    const int*   e_ggn  = (const int*)d_in[4];
    const float* W_ssn  = (const float*)d_in[5];
    const float* W_ssf  = (const float*)d_in[6];
    const float* W_ggn  = (const float*)d_in[7];
    const float* b_ssn  = (const float*)d_in[8];
    const float* b_ssf  = (const float*)d_in[9];
    const float* b_ggn  = (const float*)d_in[10];

    const int N  = in_sizes[0] / CCH;       // 50000 (src fits 16-bit pack)
    const int E  = in_sizes[2] / 2;         // 1000000
    const size_t NC = (size_t)N * CCH;
    const int NB   = (N + RPB - 1) / RPB;   // 1563 buckets per conv
    const int NBLK = (E + PCH - 1) / PCH;   // 123 partition blocks per conv

    // workspace layout
    char* w = (char*)d_ws;
    __half*   h16    = (__half*)w;   w += align256((size_t)3 * NC * 2);
    float*    dinv   = (float*)w;    w += align256((size_t)3 * N * 4);
    unsigned* bdata  = (unsigned*)w; w += align256((size_t)3 * E * 4);
    int*      sdat   = (int*)w;      w += align256((size_t)3 * E * 4);
    int*      H      = (int*)w;      w += align256((size_t)3 * NBLK * NB * 4);
    int*      cnt    = (int*)w;      w += align256((size_t)3 * NB * 4);
    int*      bstart = (int*)w;      w += align256((size_t)3 * (NB + 1) * 4);
    int*      rs     = (int*)w;      w += align256((size_t)3 * (N + 1) * 4);

    const int B = 256;

    k_zero<<<(3 * NB + B - 1) / B, B, 0, stream>>>(cnt, 3 * NB);
    k_hist<<<dim3(NBLK, 3), B, 0, stream>>>(e_ssn, e_ssf, e_ggn, H, cnt, E, NB, NBLK);
    k_bscan<<<3, 1024, 0, stream>>>(cnt, bstart, NB, E);
    k_colscan<<<dim3((NB + 3) / 4, 3), B, 0, stream>>>(H, bstart, NB, NBLK);
    k_part2<<<dim3(NBLK, 3), B, 0, stream>>>(e_ssn, e_ssf, e_ggn, H, bdata, E, NB, NBLK);
    k_sort32<<<dim3(NB, 3), B, 0, stream>>>(bdata, bstart, sdat, rs, dinv, E, N, NB);
    k_gemm_all<<<dim3((N + 15) / 16, 3), B, 0, stream>>>(x_star, x_gal,
                                                         W_ssn, W_ssf, W_ggn,
                                                         dinv, h16, N);
    k_pull<<<(2 * N + 3) / 4, B, 0, stream>>>(rs, sdat, h16, dinv,
                                              b_ssn, b_ssf, b_ggn,
                                              (float*)d_out, N, E);
}

// Round 8
// 308.175 us; speedup vs baseline: 1.3042x; 1.3042x over previous
//
#include <hip/hip_runtime.h>
#include <hip/hip_fp16.h>

#define CCH 64      // channels
#define RPB 32      // rows per bucket (dst_local fits 5 bits)
#define PCH 4096    // edges per partition block
#define NBMAX 1568  // >= NB = ceil(50000/32) = 1563
#define GR 64       // rows per gemm block

typedef int int4a __attribute__((ext_vector_type(4), aligned(4)));

// ---------------- zero int buffer ----------------
__global__ void k_zero(int* __restrict__ p, int n) {
    int i = blockIdx.x * blockDim.x + threadIdx.x;
    if (i < n) p[i] = 0;
}

// ---- pass A: per-block bucket histogram -> H[c][blk][b]; also cnt totals ----
__global__ void __launch_bounds__(256) k_hist(const int* __restrict__ e0,
        const int* __restrict__ e1, const int* __restrict__ e2,
        int* __restrict__ H, int* __restrict__ cnt, int E, int NB, int NBLK) {
    int c = blockIdx.y;
    const int* dd = ((c == 0) ? e0 : (c == 1) ? e1 : e2) + E;
    int base = blockIdx.x * PCH;
    int nE = E - base; if (nE > PCH) nE = PCH;
    __shared__ int hist[NBMAX];
    int t = threadIdx.x;
    for (int i = t; i < NB; i += 256) hist[i] = 0;
    __syncthreads();
    for (int k = t; k < nE; k += 256) atomicAdd(&hist[dd[base + k] >> 5], 1);
    __syncthreads();
    int* Hrow = H + ((size_t)c * NBLK + blockIdx.x) * NB;
    for (int i = t; i < NB; i += 256) {
        int h = hist[i];
        Hrow[i] = h;
        if (h) atomicAdd(&cnt[c * NB + i], h);
    }
}

// ---- exclusive scan of NB bucket totals per conv -> bstart ----
__global__ void __launch_bounds__(1024) k_bscan(const int* __restrict__ cnt,
        int* __restrict__ bstart, int NB, int E) {
    int c = blockIdx.x, t = threadIdx.x;
    __shared__ int sm[1024];
    int i0 = 2 * t, i1 = 2 * t + 1;
    int v0 = (i0 < NB) ? cnt[c * NB + i0] : 0;
    int v1 = (i1 < NB) ? cnt[c * NB + i1] : 0;
    sm[t] = v0 + v1;
    __syncthreads();
    #pragma unroll
    for (int off = 1; off < 1024; off <<= 1) {
        int u = (t >= off) ? sm[t - off] : 0;
        __syncthreads();
        sm[t] += u;
        __syncthreads();
    }
    int ex = sm[t] - (v0 + v1);
    if (i0 < NB) bstart[c * (NB + 1) + i0] = ex;
    if (i1 < NB) bstart[c * (NB + 1) + i1] = ex + v0;
    if (t == 0) bstart[c * (NB + 1) + NB] = E;
}

// ---- pass B: per-bucket scan over blocks (any NBLK): H <- bstart + prefix ----
__global__ void __launch_bounds__(256) k_colscan(int* __restrict__ H,
        const int* __restrict__ bstart, int NB, int NBLK) {
    int c = blockIdx.y;
    int b = blockIdx.x * 4 + (threadIdx.x >> 6);
    if (b >= NB) return;
    int l = threadIdx.x & 63;
    int* Hc = H + (size_t)c * NBLK * NB;
    int run = bstart[c * (NB + 1) + b];
    for (int c0 = 0; c0 < NBLK; c0 += 64) {
        int blk = c0 + l;
        int v = (blk < NBLK) ? Hc[(size_t)blk * NB + b] : 0;
        int s = v;
        #pragma unroll
        for (int off = 1; off < 64; off <<= 1) {
            int u = __shfl_up(s, off, 64);
            if (l >= off) s += u;
        }
        if (blk < NBLK) Hc[(size_t)blk * NB + b] = run + s - v;
        run += __shfl(s, 63, 64);
    }
}

// ---- pass C: place edges into exclusive slot ranges (LDS cursors only) ----
__global__ void __launch_bounds__(256) k_part2(const int* __restrict__ e0,
        const int* __restrict__ e1, const int* __restrict__ e2,
        const int* __restrict__ H, unsigned* __restrict__ bdata,
        int E, int NB, int NBLK) {
    int c = blockIdx.y;
    const int* ed = (c == 0) ? e0 : (c == 1) ? e1 : e2;
    int base = blockIdx.x * PCH;
    int nE = E - base; if (nE > PCH) nE = PCH;
    __shared__ int cur[NBMAX];
    const int* Hrow = H + ((size_t)c * NBLK + blockIdx.x) * NB;
    int t = threadIdx.x;
    for (int i = t; i < NB; i += 256) cur[i] = Hrow[i];
    __syncthreads();
    unsigned* bo = bdata + (size_t)c * E;
    for (int k = t; k < nE; k += 256) {
        int s = ed[base + k];
        int d = ed[E + base + k];
        int slot = atomicAdd(&cur[d >> 5], 1);
        bo[slot] = (unsigned)s | ((unsigned)(d & 31) << 16);
    }
}

// ---- within-bucket 32-way counting sort -> row-sorted src list + CSR + dinv ----
__global__ void __launch_bounds__(256) k_sort32(const unsigned* __restrict__ bdata,
        const int* __restrict__ bstart, int* __restrict__ sdat,
        int* __restrict__ rs, float* __restrict__ dinv, int E, int N, int NB) {
    int b = blockIdx.x, c = blockIdx.y;
    __shared__ int cnt[RPB];
    __shared__ int cur[RPB];
    int t = threadIdx.x;
    if (t < RPB) cnt[t] = 0;
    __syncthreads();
    int beg = bstart[c * (NB + 1) + b];
    int end = bstart[c * (NB + 1) + b + 1];
    const unsigned* bd = bdata + (size_t)c * E;
    for (int i = beg + t; i < end; i += 256) atomicAdd(&cnt[bd[i] >> 16], 1);
    __syncthreads();
    if (t < 64) {                       // wave 0: scan the 32 counters
        int v = (t < RPB) ? cnt[t] : 0;
        int s = v;
        #pragma unroll
        for (int off = 1; off < RPB; off <<= 1) {
            int u = __shfl_up(s, off, 64);
            if (t >= off) s += u;
        }
        if (t < RPB) {
            int ex = beg + s - v;       // exclusive row start
            cur[t] = ex;
            int row = b * RPB + t;
            if (row < N) {
                rs[c * (N + 1) + row] = ex;
                dinv[c * N + row] = rsqrtf((float)(v + 1));
            }
        }
        if (b == NB - 1 && t == 0) rs[c * (N + 1) + N] = E;
    }
    __syncthreads();
    int* so = sdat + (size_t)c * E;
    for (int i = beg + t; i < end; i += 256) {
        unsigned r = bd[i];
        int slot = atomicAdd(&cur[r >> 16], 1);
        so[slot] = (int)(r & 0xFFFFu);
    }
}

// ---- h16[c,row,:] = fp16( (x_row . W_c) * dinv[c,row] ), register-tiled ----
// 64 rows/block; thread = 4 rows x 4 cols. xT staged transposed (stride 65).
__global__ void __launch_bounds__(256) k_gemm_all(const float* __restrict__ xs_,
        const float* __restrict__ xg_, const float* __restrict__ W0,
        const float* __restrict__ W1, const float* __restrict__ W2,
        const float* __restrict__ dinv, __half* __restrict__ h16, int N) {
    int c = blockIdx.y;
    const float* x = (c == 2) ? xg_ : xs_;
    const float* W = (c == 0) ? W0 : (c == 1) ? W1 : W2;
    __shared__ float Ws[CCH * CCH];       // [k][col]
    __shared__ float xT[CCH * (GR + 1)];  // [k][row], stride 65
    int t = threadIdx.x;
    int row0 = blockIdx.x * GR;
    #pragma unroll
    for (int j = 0; j < 4; ++j) {
        int idx = j * 1024 + t * 4;
        *(float4*)(Ws + idx) = *(const float4*)(W + idx);
    }
    #pragma unroll
    for (int j = 0; j < 4; ++j) {
        int idx = t + j * 256;            // float4 index 0..1023
        int r = idx >> 4;                 // row 0..63
        int c0 = (idx & 15) * 4;          // k base
        int row = row0 + r;
        float4 v = make_float4(0.f, 0.f, 0.f, 0.f);
        if (row < N) v = *(const float4*)(x + (size_t)row * CCH + c0);
        xT[(c0 + 0) * (GR + 1) + r] = v.x;
        xT[(c0 + 1) * (GR + 1) + r] = v.y;
        xT[(c0 + 2) * (GR + 1) + r] = v.z;
        xT[(c0 + 3) * (GR + 1) + r] = v.w;
    }
    __syncthreads();
    int c4 = (t & 15) * 4;
    int r0 = (t >> 4) * 4;
    float4 a0 = make_float4(0.f, 0.f, 0.f, 0.f), a1 = a0, a2 = a0, a3 = a0;
    #pragma unroll 8
    for (int k = 0; k < CCH; ++k) {
        float4 wv = *(float4*)(Ws + k * CCH + c4);
        float x0 = xT[k * (GR + 1) + r0 + 0];
        float x1 = xT[k * (GR + 1) + r0 + 1];
        float x2 = xT[k * (GR + 1) + r0 + 2];
        float x3 = xT[k * (GR + 1) + r0 + 3];
        a0.x += x0 * wv.x; a0.y += x0 * wv.y; a0.z += x0 * wv.z; a0.w += x0 * wv.w;
        a1.x += x1 * wv.x; a1.y += x1 * wv.y; a1.z += x1 * wv.z; a1.w += x1 * wv.w;
        a2.x += x2 * wv.x; a2.y += x2 * wv.y; a2.z += x2 * wv.z; a2.w += x2 * wv.w;
        a3.x += x3 * wv.x; a3.y += x3 * wv.y; a3.z += x3 * wv.z; a3.w += x3 * wv.w;
    }
    const float* dv = dinv + c * N;
    __half* hc = h16 + (size_t)c * N * CCH;
    float4 av[4] = {a0, a1, a2, a3};
    #pragma unroll
    for (int i = 0; i < 4; ++i) {
        int row = row0 + r0 + i;
        if (row < N) {
            float dd = dv[row];
            union { __half2 h2[2]; float2 f2; } u;
            u.h2[0] = __floats2half2_rn(av[i].x * dd, av[i].y * dd);
            u.h2[1] = __floats2half2_rn(av[i].z * dd, av[i].w * dd);
            *(float2*)(hc + (size_t)row * CCH + c4) = u.f2;
        }
    }
}

// ---- gather one fp16 channel-pair ----
__device__ __forceinline__ float2 gat(const __half* __restrict__ hc, int s, int l32) {
    __half2 h = ((const __half2*)(hc + (size_t)s * CCH))[l32];
    float2 r; r.x = __half2float(__low2half(h)); r.y = __half2float(__high2half(h));
    return r;
}

// ---- half-wave paired pull: lanes 0-31 = even edges, 32-63 = odd edges.
// Each lane accumulates channels (2*l32, 2*l32+1). int4 index loads. ----
__device__ __forceinline__ float2 pull2(const int* __restrict__ sd,
        int beg, int end, const __half* __restrict__ hc, int half, int l32) {
    float2 acc = make_float2(0.f, 0.f);
    int i = beg;
    for (; i + 7 < end; i += 8) {       // 8 edges, 4 per half-wave, 4 gathers in flight
        int4a q0 = *(const int4a*)(sd + i);
        int4a q1 = *(const int4a*)(sd + i + 4);
        int s0 = half ? q0.y : q0.x;
        int s1 = half ? q0.w : q0.z;
        int s2 = half ? q1.y : q1.x;
        int s3 = half ? q1.w : q1.z;
        float2 v0 = gat(hc, s0, l32);
        float2 v1 = gat(hc, s1, l32);
        float2 v2 = gat(hc, s2, l32);
        float2 v3 = gat(hc, s3, l32);
        acc.x += (v0.x + v1.x) + (v2.x + v3.x);
        acc.y += (v0.y + v1.y) + (v2.y + v3.y);
    }
    for (int j = i + half; j < end; j += 2) {
        float2 v = gat(hc, sd[j], l32);
        acc.x += v.x; acc.y += v.y;
    }
    return acc;
}

// ---- fused pull: wave per row, no LDS, single float2 store per lane ----
__global__ void __launch_bounds__(256) k_pull(const int* __restrict__ rs,
        const int* __restrict__ sdat, const __half* __restrict__ h16,
        const float* __restrict__ dinv,
        const float* __restrict__ b0, const float* __restrict__ b1,
        const float* __restrict__ b2,
        float* __restrict__ out, int N, int E) {
    int row = blockIdx.x * 4 + (threadIdx.x >> 6);
    if (row >= 2 * N) return;
    int lane = threadIdx.x & 63;
    int half = lane >> 5;
    int l32 = lane & 31;
    size_t NC = (size_t)N * CCH;
    if (row < N) {                          // star: conv0 + conv1
        const int* rs1 = rs + (N + 1);
        float2 a0 = pull2(sdat,     rs[row],  rs[row + 1],  h16,      half, l32);
        float2 a1 = pull2(sdat + E, rs1[row], rs1[row + 1], h16 + NC, half, l32);
        a0.x += __shfl_xor(a0.x, 32, 64); a0.y += __shfl_xor(a0.y, 32, 64);
        a1.x += __shfl_xor(a1.x, 32, 64); a1.y += __shfl_xor(a1.y, 32, 64);
        float dd0 = dinv[row], dd1 = dinv[N + row];
        float2 s0 = gat(h16,      row, l32);
        float2 s1 = gat(h16 + NC, row, l32);
        float2 bv0 = ((const float2*)b0)[l32];
        float2 bv1 = ((const float2*)b1)[l32];
        float2 o;
        o.x = (a0.x + s0.x) * dd0 + (a1.x + s1.x) * dd1 + bv0.x + bv1.x;
        o.y = (a0.y + s0.y) * dd0 + (a1.y + s1.y) * dd1 + bv0.y + bv1.y;
        if (lane < 32) ((float2*)(out + (size_t)row * CCH))[l32] = o;
    } else {                                // gal: conv2
        int r = row - N;
        const int* rs2 = rs + 2 * (N + 1);
        float2 a2 = pull2(sdat + 2 * (size_t)E, rs2[r], rs2[r + 1],
                          h16 + 2 * NC, half, l32);
        a2.x += __shfl_xor(a2.x, 32, 64); a2.y += __shfl_xor(a2.y, 32, 64);
        float dd2 = dinv[2 * N + r];
        float2 s2 = gat(h16 + 2 * NC, r, l32);
        float2 bv2 = ((const float2*)b2)[l32];
        float2 o;
        o.x = (a2.x + s2.x) * dd2 + bv2.x;
        o.y = (a2.y + s2.y) * dd2 + bv2.y;
        if (lane < 32) ((float2*)(out + NC + (size_t)r * CCH))[l32] = o;
    }
}

static inline size_t align256(size_t x) { return (x + 255) & ~(size_t)255; }

extern "C" void kernel_launch(void* const* d_in, const int* in_sizes, int n_in,
                              void* d_out, int out_size, void* d_ws, size_t ws_size,
                              hipStream_t stream) {
    const float* x_star = (const float*)d_in[0];
    const float* x_gal  = (const float*)d_in[1];
    const int*   e_ssn  = (const int*)d_in[2];
    const int*   e_ssf  = (const int*)d_in[3];
    const int*   e_ggn  = (const int*)d_in[4];
    const float* W_ssn  = (const float*)d_in[5];
    const float* W_ssf  = (const float*)d_in[6];
    const float* W_ggn  = (const float*)d_in[7];
    const float* b_ssn  = (const float*)d_in[8];
    const float* b_ssf  = (const float*)d_in[9];
    const float* b_ggn  = (const float*)d_in[10];

    const int N  = in_sizes[0] / CCH;       // 50000 (src fits 16-bit pack)
    const int E  = in_sizes[2] / 2;         // 1000000
    const size_t NC = (size_t)N * CCH;
    const int NB   = (N + RPB - 1) / RPB;   // 1563 buckets per conv
    const int NBLK = (E + PCH - 1) / PCH;   // 245 partition blocks per conv

    // workspace layout
    char* w = (char*)d_ws;
    __half*   h16    = (__half*)w;   w += align256((size_t)3 * NC * 2);
    float*    dinv   = (float*)w;    w += align256((size_t)3 * N * 4);
    unsigned* bdata  = (unsigned*)w; w += align256((size_t)3 * E * 4);
    int*      sdat   = (int*)w;      w += align256((size_t)3 * E * 4);
    int*      H      = (int*)w;      w += align256((size_t)3 * NBLK * NB * 4);
    int*      cnt    = (int*)w;      w += align256((size_t)3 * NB * 4);
    int*      bstart = (int*)w;      w += align256((size_t)3 * (NB + 1) * 4);
    int*      rs     = (int*)w;      w += align256((size_t)3 * (N + 1) * 4);

    const int B = 256;

    k_zero<<<(3 * NB + B - 1) / B, B, 0, stream>>>(cnt, 3 * NB);
    k_hist<<<dim3(NBLK, 3), B, 0, stream>>>(e_ssn, e_ssf, e_ggn, H, cnt, E, NB, NBLK);
    k_bscan<<<3, 1024, 0, stream>>>(cnt, bstart, NB, E);
    k_colscan<<<dim3((NB + 3) / 4, 3), B, 0, stream>>>(H, bstart, NB, NBLK);
    k_part2<<<dim3(NBLK, 3), B, 0, stream>>>(e_ssn, e_ssf, e_ggn, H, bdata, E, NB, NBLK);
    k_sort32<<<dim3(NB, 3), B, 0, stream>>>(bdata, bstart, sdat, rs, dinv, E, N, NB);
    k_gemm_all<<<dim3((N + GR - 1) / GR, 3), B, 0, stream>>>(x_star, x_gal,
                                                             W_ssn, W_ssf, W_ggn,
                                                             dinv, h16, N);
    k_pull<<<(2 * N + 3) / 4, B, 0, stream>>>(rs, sdat, h16, dinv,
                                              b_ssn, b_ssf, b_ggn,
                                              (float*)d_out, N, E);
}

// Round 9
// 271.850 us; speedup vs baseline: 1.4785x; 1.1336x over previous
//
#include <hip/hip_runtime.h>
#include <hip/hip_fp16.h>

#define CCH 64      // channels
#define RPB 32      // rows per bucket (dst_local fits 5 bits)
#define PCH 4096    // edges per partition block
#define NBMAX 1568  // >= NB = ceil(50000/32) = 1563
#define GR 64       // rows per gemm block
#define SG 4        // buckets per sort block

typedef int int4a __attribute__((ext_vector_type(4), aligned(4)));

// ---------------- zero int buffer ----------------
__global__ void k_zero(int* __restrict__ p, int n) {
    int i = blockIdx.x * blockDim.x + threadIdx.x;
    if (i < n) p[i] = 0;
}

// ---- pass A: per-block bucket histogram -> H[c][blk][b]; also cnt totals ----
__global__ void __launch_bounds__(256) k_hist(const int* __restrict__ e0,
        const int* __restrict__ e1, const int* __restrict__ e2,
        int* __restrict__ H, int* __restrict__ cnt, int E, int NB, int NBLK) {
    int c = blockIdx.y;
    const int* dd = ((c == 0) ? e0 : (c == 1) ? e1 : e2) + E;
    int base = blockIdx.x * PCH;
    int nE = E - base; if (nE > PCH) nE = PCH;
    __shared__ int hist[NBMAX];
    int t = threadIdx.x;
    for (int i = t; i < NB; i += 256) hist[i] = 0;
    __syncthreads();
    for (int k = t; k < nE; k += 256) atomicAdd(&hist[dd[base + k] >> 5], 1);
    __syncthreads();
    int* Hrow = H + ((size_t)c * NBLK + blockIdx.x) * NB;
    for (int i = t; i < NB; i += 256) {
        int h = hist[i];
        Hrow[i] = h;
        if (h) atomicAdd(&cnt[c * NB + i], h);
    }
}

// ---- exclusive scan of NB bucket totals per conv -> bstart ----
__global__ void __launch_bounds__(1024) k_bscan(const int* __restrict__ cnt,
        int* __restrict__ bstart, int NB, int E) {
    int c = blockIdx.x, t = threadIdx.x;
    __shared__ int sm[1024];
    int i0 = 2 * t, i1 = 2 * t + 1;
    int v0 = (i0 < NB) ? cnt[c * NB + i0] : 0;
    int v1 = (i1 < NB) ? cnt[c * NB + i1] : 0;
    sm[t] = v0 + v1;
    __syncthreads();
    #pragma unroll
    for (int off = 1; off < 1024; off <<= 1) {
        int u = (t >= off) ? sm[t - off] : 0;
        __syncthreads();
        sm[t] += u;
        __syncthreads();
    }
    int ex = sm[t] - (v0 + v1);
    if (i0 < NB) bstart[c * (NB + 1) + i0] = ex;
    if (i1 < NB) bstart[c * (NB + 1) + i1] = ex + v0;
    if (t == 0) bstart[c * (NB + 1) + NB] = E;
}

// ---- pass B: per-bucket scan over blocks (any NBLK): H <- bstart + prefix ----
__global__ void __launch_bounds__(256) k_colscan(int* __restrict__ H,
        const int* __restrict__ bstart, int NB, int NBLK) {
    int c = blockIdx.y;
    int b = blockIdx.x * 4 + (threadIdx.x >> 6);
    if (b >= NB) return;
    int l = threadIdx.x & 63;
    int* Hc = H + (size_t)c * NBLK * NB;
    int run = bstart[c * (NB + 1) + b];
    for (int c0 = 0; c0 < NBLK; c0 += 64) {
        int blk = c0 + l;
        int v = (blk < NBLK) ? Hc[(size_t)blk * NB + b] : 0;
        int s = v;
        #pragma unroll
        for (int off = 1; off < 64; off <<= 1) {
            int u = __shfl_up(s, off, 64);
            if (l >= off) s += u;
        }
        if (blk < NBLK) Hc[(size_t)blk * NB + b] = run + s - v;
        run += __shfl(s, 63, 64);
    }
}

// ---- pass C: place edges into exclusive slot ranges (LDS cursors only) ----
__global__ void __launch_bounds__(256) k_part2(const int* __restrict__ e0,
        const int* __restrict__ e1, const int* __restrict__ e2,
        const int* __restrict__ H, unsigned* __restrict__ bdata,
        int E, int NB, int NBLK) {
    int c = blockIdx.y;
    const int* ed = (c == 0) ? e0 : (c == 1) ? e1 : e2;
    int base = blockIdx.x * PCH;
    int nE = E - base; if (nE > PCH) nE = PCH;
    __shared__ int cur[NBMAX];
    const int* Hrow = H + ((size_t)c * NBLK + blockIdx.x) * NB;
    int t = threadIdx.x;
    for (int i = t; i < NB; i += 256) cur[i] = Hrow[i];
    __syncthreads();
    unsigned* bo = bdata + (size_t)c * E;
    for (int k = t; k < nE; k += 256) {
        int s = ed[base + k];
        int d = ed[E + base + k];
        int slot = atomicAdd(&cur[d >> 5], 1);
        bo[slot] = (unsigned)s | ((unsigned)(d & 31) << 16);
    }
}

// ---- within-bucket 32-way counting sort, SG buckets per block ----
__global__ void __launch_bounds__(256) k_sort32(const unsigned* __restrict__ bdata,
        const int* __restrict__ bstart, int* __restrict__ sdat,
        int* __restrict__ rs, float* __restrict__ dinv, int E, int N, int NB) {
    int c = blockIdx.y;
    int b0 = blockIdx.x * SG;
    __shared__ int cnt[SG * RPB];
    __shared__ int cur[SG * RPB];
    __shared__ int sb[SG + 1];
    int t = threadIdx.x;
    if (t < SG * RPB) cnt[t] = 0;
    if (t <= SG) {
        int b = b0 + t; if (b > NB) b = NB;
        sb[t] = bstart[c * (NB + 1) + b];
    }
    __syncthreads();
    int s0 = sb[0], s1 = sb[1], s2 = sb[2], s3 = sb[3], s4 = sb[SG];
    const unsigned* bd = bdata + (size_t)c * E;
    for (int i = s0 + t; i < s4; i += 256) {
        int g = (i >= s1) + (i >= s2) + (i >= s3);
        atomicAdd(&cnt[g * RPB + (int)(bd[i] >> 16)], 1);
    }
    __syncthreads();
    if (t < SG * RPB) {        // waves 0-1; 32-lane groups align with buckets
        int v = cnt[t];
        int s = v;
        #pragma unroll
        for (int off = 1; off < RPB; off <<= 1) {
            int u = __shfl_up(s, off, RPB);
            if ((t & (RPB - 1)) >= off) s += u;
        }
        int g = t >> 5, r = t & 31;
        int ex = sb[g] + s - v;
        cur[t] = ex;
        int row = (b0 + g) * RPB + r;
        if (b0 + g < NB && row < N) {
            rs[c * (N + 1) + row] = ex;
            dinv[c * N + row] = rsqrtf((float)(v + 1));
        }
    }
    if (blockIdx.x == 0 && t == 0) rs[c * (N + 1) + N] = E;
    __syncthreads();
    int* so = sdat + (size_t)c * E;
    for (int i = s0 + t; i < s4; i += 256) {
        unsigned r = bd[i];
        int g = (i >= s1) + (i >= s2) + (i >= s3);
        int slot = atomicAdd(&cur[g * RPB + (int)(r >> 16)], 1);
        so[slot] = (int)(r & 0xFFFFu);
    }
}

// ---- h16[c,row,:] = fp16( (x_row . W_c) * dinv[c,row] ), register-tiled ----
__global__ void __launch_bounds__(256) k_gemm_all(const float* __restrict__ xs_,
        const float* __restrict__ xg_, const float* __restrict__ W0,
        const float* __restrict__ W1, const float* __restrict__ W2,
        const float* __restrict__ dinv, __half* __restrict__ h16, int N) {
    int c = blockIdx.y;
    const float* x = (c == 2) ? xg_ : xs_;
    const float* W = (c == 0) ? W0 : (c == 1) ? W1 : W2;
    __shared__ float Ws[CCH * CCH];       // [k][col]
    __shared__ float xT[CCH * (GR + 1)];  // [k][row], stride 65
    int t = threadIdx.x;
    int row0 = blockIdx.x * GR;
    #pragma unroll
    for (int j = 0; j < 4; ++j) {
        int idx = j * 1024 + t * 4;
        *(float4*)(Ws + idx) = *(const float4*)(W + idx);
    }
    #pragma unroll
    for (int j = 0; j < 4; ++j) {
        int idx = t + j * 256;
        int r = idx >> 4;
        int c0 = (idx & 15) * 4;
        int row = row0 + r;
        float4 v = make_float4(0.f, 0.f, 0.f, 0.f);
        if (row < N) v = *(const float4*)(x + (size_t)row * CCH + c0);
        xT[(c0 + 0) * (GR + 1) + r] = v.x;
        xT[(c0 + 1) * (GR + 1) + r] = v.y;
        xT[(c0 + 2) * (GR + 1) + r] = v.z;
        xT[(c0 + 3) * (GR + 1) + r] = v.w;
    }
    __syncthreads();
    int c4 = (t & 15) * 4;
    int r0 = (t >> 4) * 4;
    float4 a0 = make_float4(0.f, 0.f, 0.f, 0.f), a1 = a0, a2 = a0, a3 = a0;
    #pragma unroll 8
    for (int k = 0; k < CCH; ++k) {
        float4 wv = *(float4*)(Ws + k * CCH + c4);
        float x0 = xT[k * (GR + 1) + r0 + 0];
        float x1 = xT[k * (GR + 1) + r0 + 1];
        float x2 = xT[k * (GR + 1) + r0 + 2];
        float x3 = xT[k * (GR + 1) + r0 + 3];
        a0.x += x0 * wv.x; a0.y += x0 * wv.y; a0.z += x0 * wv.z; a0.w += x0 * wv.w;
        a1.x += x1 * wv.x; a1.y += x1 * wv.y; a1.z += x1 * wv.z; a1.w += x1 * wv.w;
        a2.x += x2 * wv.x; a2.y += x2 * wv.y; a2.z += x2 * wv.z; a2.w += x2 * wv.w;
        a3.x += x3 * wv.x; a3.y += x3 * wv.y; a3.z += x3 * wv.z; a3.w += x3 * wv.w;
    }
    const float* dv = dinv + c * N;
    __half* hc = h16 + (size_t)c * N * CCH;
    float4 av[4] = {a0, a1, a2, a3};
    #pragma unroll
    for (int i = 0; i < 4; ++i) {
        int row = row0 + r0 + i;
        if (row < N) {
            float dd = dv[row];
            union { __half2 h2[2]; float2 f2; } u;
            u.h2[0] = __floats2half2_rn(av[i].x * dd, av[i].y * dd);
            u.h2[1] = __floats2half2_rn(av[i].z * dd, av[i].w * dd);
            *(float2*)(hc + (size_t)row * CCH + c4) = u.f2;
        }
    }
}

// ---- gather one fp16 channel-pair ----
__device__ __forceinline__ float2 gat(const __half* __restrict__ hc, int s, int l32) {
    __half2 h = ((const __half2*)(hc + (size_t)s * CCH))[l32];
    float2 r; r.x = __half2float(__low2half(h)); r.y = __half2float(__high2half(h));
    return r;
}

// ---- fused pull: wave per row; half-wave0/1 walk the two conv lists (star)
//      or the two halves of one list (gal) in LOCKSTEP. No LDS. ----
__global__ void __launch_bounds__(256) k_pull(const int* __restrict__ rs,
        const int* __restrict__ sdat, const __half* __restrict__ h16,
        const float* __restrict__ dinv,
        const float* __restrict__ b0, const float* __restrict__ b1,
        const float* __restrict__ b2,
        float* __restrict__ out, int N, int E) {
    int row = blockIdx.x * 4 + (threadIdx.x >> 6);
    if (row >= 2 * N) return;
    int lane = threadIdx.x & 63;
    int half = lane >> 5;
    int l32 = lane & 31;
    size_t NC = (size_t)N * CCH;

    const __half* hcL;
    const int* sdL;
    int beg, end;
    float ddL;
    float2 sL, bias;
    float* op;
    if (row < N) {                          // star: half0=conv0, half1=conv1
        const int* rsA = rs + half * (N + 1);
        beg = rsA[row]; end = rsA[row + 1];
        hcL = h16 + (size_t)half * NC;
        sdL = sdat + (size_t)half * E;
        ddL = dinv[half * N + row];
        sL = gat(hcL, row, l32);
        float2 bv0 = ((const float2*)b0)[l32];
        float2 bv1 = ((const float2*)b1)[l32];
        bias.x = bv0.x + bv1.x; bias.y = bv0.y + bv1.y;
        op = out + (size_t)row * CCH;
    } else {                                // gal: range split across halves
        int r = row - N;
        const int* rs2 = rs + 2 * (N + 1);
        int bg = rs2[r], eg = rs2[r + 1];
        int mid = (bg + eg) >> 1;
        beg = half ? mid : bg;
        end = half ? eg : mid;
        hcL = h16 + 2 * NC;
        sdL = sdat + 2 * (size_t)E;
        ddL = dinv[2 * N + r];
        sL = half ? make_float2(0.f, 0.f) : gat(hcL, r, l32);
        bias = ((const float2*)b2)[l32];
        op = out + NC + (size_t)r * CCH;
    }

    float2 acc = make_float2(0.f, 0.f);
    int i = beg;
    for (; i + 7 < end; i += 8) {           // per-half 8-edge unroll, lockstep
        int4a q0 = *(const int4a*)(sdL + i);
        int4a q1 = *(const int4a*)(sdL + i + 4);
        float2 v0 = gat(hcL, q0.x, l32);
        float2 v1 = gat(hcL, q0.y, l32);
        float2 v2 = gat(hcL, q0.z, l32);
        float2 v3 = gat(hcL, q0.w, l32);
        float2 v4 = gat(hcL, q1.x, l32);
        float2 v5 = gat(hcL, q1.y, l32);
        float2 v6 = gat(hcL, q1.z, l32);
        float2 v7 = gat(hcL, q1.w, l32);
        acc.x += ((v0.x + v1.x) + (v2.x + v3.x)) + ((v4.x + v5.x) + (v6.x + v7.x));
        acc.y += ((v0.y + v1.y) + (v2.y + v3.y)) + ((v4.y + v5.y) + (v6.y + v7.y));
    }
    for (; i + 3 < end; i += 4) {
        int4a q0 = *(const int4a*)(sdL + i);
        float2 v0 = gat(hcL, q0.x, l32);
        float2 v1 = gat(hcL, q0.y, l32);
        float2 v2 = gat(hcL, q0.z, l32);
        float2 v3 = gat(hcL, q0.w, l32);
        acc.x += (v0.x + v1.x) + (v2.x + v3.x);
        acc.y += (v0.y + v1.y) + (v2.y + v3.y);
    }
    for (; i < end; ++i) {
        float2 v = gat(hcL, sdL[i], l32);
        acc.x += v.x; acc.y += v.y;
    }
    float2 t;
    t.x = (acc.x + sL.x) * ddL;
    t.y = (acc.y + sL.y) * ddL;
    float2 o;
    o.x = t.x + __shfl_xor(t.x, 32, 64);
    o.y = t.y + __shfl_xor(t.y, 32, 64);
    if (lane < 32) {
        o.x += bias.x; o.y += bias.y;
        ((float2*)op)[l32] = o;
    }
}

static inline size_t align256(size_t x) { return (x + 255) & ~(size_t)255; }

extern "C" void kernel_launch(void* const* d_in, const int* in_sizes, int n_in,
                              void* d_out, int out_size, void* d_ws, size_t ws_size,
                              hipStream_t stream) {
    const float* x_star = (const float*)d_in[0];
    const float* x_gal  = (const float*)d_in[1];
    const int*   e_ssn  = (const int*)d_in[2];
    const int*   e_ssf  = (const int*)d_in[3];
    const int*   e_ggn  = (const int*)d_in[4];
    const float* W_ssn  = (const float*)d_in[5];
    const float* W_ssf  = (const float*)d_in[6];
    const float* W_ggn  = (const float*)d_in[7];
    const float* b_ssn  = (const float*)d_in[8];
    const float* b_ssf  = (const float*)d_in[9];
    const float* b_ggn  = (const float*)d_in[10];

    const int N  = in_sizes[0] / CCH;       // 50000 (src fits 16-bit pack)
    const int E  = in_sizes[2] / 2;         // 1000000
    const size_t NC = (size_t)N * CCH;
    const int NB   = (N + RPB - 1) / RPB;   // 1563 buckets per conv
    const int NBLK = (E + PCH - 1) / PCH;   // 245 partition blocks per conv

    // workspace layout
    char* w = (char*)d_ws;
    __half*   h16    = (__half*)w;   w += align256((size_t)3 * NC * 2);
    float*    dinv   = (float*)w;    w += align256((size_t)3 * N * 4);
    unsigned* bdata  = (unsigned*)w; w += align256((size_t)3 * E * 4);
    int*      sdat   = (int*)w;      w += align256((size_t)3 * E * 4);
    int*      H      = (int*)w;      w += align256((size_t)3 * NBLK * NB * 4);
    int*      cnt    = (int*)w;      w += align256((size_t)3 * NB * 4);
    int*      bstart = (int*)w;      w += align256((size_t)3 * (NB + 1) * 4);
    int*      rs     = (int*)w;      w += align256((size_t)3 * (N + 1) * 4);

    const int B = 256;

    k_zero<<<(3 * NB + B - 1) / B, B, 0, stream>>>(cnt, 3 * NB);
    k_hist<<<dim3(NBLK, 3), B, 0, stream>>>(e_ssn, e_ssf, e_ggn, H, cnt, E, NB, NBLK);
    k_bscan<<<3, 1024, 0, stream>>>(cnt, bstart, NB, E);
    k_colscan<<<dim3((NB + 3) / 4, 3), B, 0, stream>>>(H, bstart, NB, NBLK);
    k_part2<<<dim3(NBLK, 3), B, 0, stream>>>(e_ssn, e_ssf, e_ggn, H, bdata, E, NB, NBLK);
    k_sort32<<<dim3((NB + SG - 1) / SG, 3), B, 0, stream>>>(bdata, bstart, sdat,
                                                            rs, dinv, E, N, NB);
    k_gemm_all<<<dim3((N + GR - 1) / GR, 3), B, 0, stream>>>(x_star, x_gal,
                                                             W_ssn, W_ssf, W_ggn,
                                                             dinv, h16, N);
    k_pull<<<(2 * N + 3) / 4, B, 0, stream>>>(rs, sdat, h16, dinv,
                                              b_ssn, b_ssf, b_ggn,
                                              (float*)d_out, N, E);
}